// Round 13
// baseline (117.001 us; speedup 1.0000x reference)
//
#include <hip/hip_runtime.h>
#include <hip/hip_bf16.h>
#include <math.h>

// B=2, C=128, T=5 (Tc=4 ctx), H=W=48, heads=64, PATCH=7 (pad 3), K=196.
#define BATCH 2
#define CCH 128
#define TT 5
#define TC 4
#define HH 48
#define WW 48
#define HWPIX 2304
#define NHEAD 64
#define PAD 3
#define XSTRIDE (TT*HWPIX)      // per-channel stride in x
#define ROWP 54                 // 48 + 2*3 padded rows
#define COLP 56                 // 48 + 2*3 padded cols (+2 align slack)
#define PLANE (ROWP*COLP*NHEAD) // elements per (b,t) plane

typedef unsigned short bf16_t;

static __device__ __forceinline__ bf16_t f2bf(float f) {
    unsigned u = __float_as_uint(f);
    u += 0x7FFFu + ((u >> 16) & 1u);          // round-to-nearest-even
    return (bf16_t)(u >> 16);
}
static __device__ __forceinline__ float bf_lo(unsigned u) {
    return __uint_as_float(u << 16);
}
static __device__ __forceinline__ float bf_hi(unsigned u) {
    return __uint_as_float(u & 0xFFFF0000u);
}

#if defined(__has_builtin)
#if __has_builtin(__builtin_amdgcn_fdot2_f32_bf16) && __has_builtin(__builtin_amdgcn_perm)
#define HAVE_DOT2 1
#endif
#endif

#ifdef HAVE_DOT2
typedef __bf16 bf16x2_t __attribute__((ext_vector_type(2)));
static __device__ __forceinline__ float dot2bf(unsigned g2, unsigned a2, float c) {
    return __builtin_amdgcn_fdot2_f32_bf16(
        __builtin_bit_cast(bf16x2_t, g2), __builtin_bit_cast(bf16x2_t, a2), c, false);
}
static __device__ __forceinline__ unsigned perm_lo(unsigned a, unsigned b) {
    return __builtin_amdgcn_perm(a, b, 0x05040100u);
}
static __device__ __forceinline__ unsigned perm_hi(unsigned a, unsigned b) {
    return __builtin_amdgcn_perm(a, b, 0x07060302u);
}
#else
static __device__ __forceinline__ float dot2bf(unsigned g2, unsigned a2, float c) {
    return c + bf_lo(g2) * bf_lo(a2) + bf_hi(g2) * bf_hi(a2);
}
#endif

static __device__ __forceinline__ uint4 pack8(const float* s) {
    uint4 o;
    o.x = (unsigned)f2bf(s[0]) | ((unsigned)f2bf(s[1]) << 16);
    o.y = (unsigned)f2bf(s[2]) | ((unsigned)f2bf(s[3]) << 16);
    o.z = (unsigned)f2bf(s[4]) | ((unsigned)f2bf(s[5]) << 16);
    o.w = (unsigned)f2bf(s[6]) | ((unsigned)f2bf(s[7]) << 16);
    return o;
}

// ---------------------------------------------------------------------------
// K1: projections, fully LDS-resident inner loop, bf16 dot2 math.
// Weights converted fp32->bf16-pair inline during staging (wtrans deleted).
// Block = 16 px of one (b,t). lane = head, wave = px-quad.
// q bf16; phi_b/g_b bf16 padded planes (replicate borders).
// ---------------------------------------------------------------------------
__global__ __launch_bounds__(256) void proj_kernel(
    const float* __restrict__ x,
    const float* __restrict__ w_theta,
    const float* __restrict__ w_phi,
    const float* __restrict__ w_g,
    bf16_t* __restrict__ q_b,
    bf16_t* __restrict__ phi_b,
    bf16_t* __restrict__ g_b)
{
    __shared__ unsigned xs[16 * 68];    // 4.25 KB (bf16 c-pairs, pitch 68)
    __shared__ uint4 wlA[1024];         // 16 KB  [ck<<6 | h]
    __shared__ uint4 wlB[1024];         // 16 KB

    const int bt   = blockIdx.y;        // 0..9
    const int b    = bt / TT;
    const int t    = bt % TT;
    const int tid  = threadIdx.x;
    const int lane = tid & 63;
    const int wv   = tid >> 6;
    const int p0   = blockIdx.x * 16;

    // ---- stage weights into LDS (fp32 -> bf16 pairs inline) ----
    {
        const float* wA = (t == 0) ? w_theta : w_phi;
#pragma unroll
        for (int i = 0; i < 4; ++i) {
            const int idx = i * 256 + tid;   // 0..1023
            const int h   = idx >> 4;
            const int ck  = idx & 15;
            wlA[(ck << 6) | h] = pack8(wA + h * CCH + ck * 8);
        }
        if (t != 0) {
#pragma unroll
            for (int i = 0; i < 4; ++i) {
                const int idx = i * 256 + tid;
                const int h   = idx >> 4;
                const int ck  = idx & 15;
                wlB[(ck << 6) | h] = pack8(w_g + h * CCH + ck * 8);
            }
        }
    }

    // ---- stage x tile as bf16 pairs (lanes over px: coalesced) ----
    {
        const float* xsrc = x + ((size_t)(b * CCH) * TT + t) * HWPIX + p0;
#pragma unroll
        for (int i = 0; i < 4; ++i) {
            const int idx = i * 256 + tid;  // 0..1023
            const int cp  = idx >> 4;       // c-pair 0..63
            const int px  = idx & 15;
            const float a0 = xsrc[(size_t)(2 * cp)     * XSTRIDE + px];
            const float a1 = xsrc[(size_t)(2 * cp + 1) * XSTRIDE + px];
            xs[px * 68 + cp] = (unsigned)f2bf(a0) | ((unsigned)f2bf(a1) << 16);
        }
    }
    __syncthreads();

    const int pxb = wv * 4;

    if (t == 0) {
        float acc[4] = {0.f, 0.f, 0.f, 0.f};
#pragma unroll 4
        for (int ck = 0; ck < 16; ++ck) {
            const uint4 wa = wlA[(ck << 6) | lane];
#pragma unroll
            for (int p = 0; p < 4; ++p) {
                const uint4 xv = *(const uint4*)&xs[(pxb + p) * 68 + (ck << 2)];
                acc[p] = dot2bf(wa.x, xv.x, acc[p]);
                acc[p] = dot2bf(wa.y, xv.y, acc[p]);
                acc[p] = dot2bf(wa.z, xv.z, acc[p]);
                acc[p] = dot2bf(wa.w, xv.w, acc[p]);
            }
        }
#pragma unroll
        for (int p = 0; p < 4; ++p)
            q_b[((size_t)b * HWPIX + p0 + pxb + p) * NHEAD + lane] = f2bf(acc[p]);
    } else {
        float accp[4] = {0.f, 0.f, 0.f, 0.f};
        float accg[4] = {0.f, 0.f, 0.f, 0.f};
#pragma unroll 4
        for (int ck = 0; ck < 16; ++ck) {
            const uint4 wa = wlA[(ck << 6) | lane];
            const uint4 wb = wlB[(ck << 6) | lane];
#pragma unroll
            for (int p = 0; p < 4; ++p) {
                const uint4 xv = *(const uint4*)&xs[(pxb + p) * 68 + (ck << 2)];
                accp[p] = dot2bf(wa.x, xv.x, accp[p]);
                accp[p] = dot2bf(wa.y, xv.y, accp[p]);
                accp[p] = dot2bf(wa.z, xv.z, accp[p]);
                accp[p] = dot2bf(wa.w, xv.w, accp[p]);
                accg[p] = dot2bf(wb.x, xv.x, accg[p]);
                accg[p] = dot2bf(wb.y, xv.y, accg[p]);
                accg[p] = dot2bf(wb.z, xv.z, accg[p]);
                accg[p] = dot2bf(wb.w, xv.w, accg[p]);
            }
        }
        const size_t base = (size_t)(b * TC + (t - 1)) * PLANE;
#pragma unroll
        for (int p = 0; p < 4; ++p) {
            const int pix = p0 + pxb + p;
            const int X = pix / WW;
            const int Y = pix % WW;
            const int rs = (X == 0) ? 0 : (X + PAD);
            const int rn = (X == 0 || X == HH - 1) ? (PAD + 1) : 1;
            const int cs = (Y == 0) ? 0 : (Y + PAD);
            const int cn = (Y == 0 || Y == WW - 1) ? (PAD + 1) : 1;
            const bf16_t vp = f2bf(accp[p]);
            const bf16_t vg = f2bf(accg[p]);
            for (int r = 0; r < rn; ++r)
                for (int c = 0; c < cn; ++c) {
                    const size_t pos = base + ((size_t)(rs + r) * COLP + (cs + c)) * NHEAD + lane;
                    phi_b[pos] = vp;
                    g_b[pos]   = vg;
                }
        }
    }
}

// ---------------------------------------------------------------------------
// K2: per-t attention partial. DOUBLE-BUFFERED windows: phi->win1, g->win2
// staged together (both fetch latencies overlap), ONE barrier total; logits,
// softmax, ls2 pack, and y-accumulation are all same-wave thereafter.
// ---------------------------------------------------------------------------
__global__ __launch_bounds__(256) void attn_kernel(
    const bf16_t* __restrict__ q_b,
    const bf16_t* __restrict__ phi_b,
    const bf16_t* __restrict__ g_b,
    float* __restrict__ part_ml,
    bf16_t* __restrict__ part_y)
{
    __shared__ bf16_t win1[154 * NHEAD];    // 19.25 KB phi (swizzled)
    __shared__ bf16_t win2[154 * NHEAD];    // 19.25 KB g
    __shared__ float ls[16][52];            // 49 exp-weights per px
    __shared__ unsigned ls2[16][26];        // packed bf16 weight pairs
    __shared__ unsigned prow[26];           // (row0 | row1<<16) per pair

    const int tid = threadIdx.x;
    const int px  = tid >> 4;
    const int sub = tid & 15;
    const int bi  = blockIdx.x;
    const int btc = bi & 7;                 // b*4 + t
    const int b   = btc >> 2;
    const int t   = btc & 3;
    const int rest = bi >> 3;               // 0..143
    const int Y0  = (rest % 3) * 16;
    const int X   = rest / 3;               // 0..47
    const int gpix = X * WW + Y0 + px;

    uint4 qu[8];
    {
        const uint4* qs = (const uint4*)(q_b + ((size_t)b * HWPIX + gpix) * NHEAD);
#pragma unroll
        for (int ch = 0; ch < 8; ++ch) qu[ch] = qs[ch];
    }

    if (tid < 25) {
        const int k0 = 2 * tid;
        const int k1 = (k0 + 1 < 49) ? k0 + 1 : 48;
        const unsigned r0 = (k0 / 7) * 22 + (k0 % 7);
        const unsigned r1 = (k1 / 7) * 22 + (k1 % 7);
        prow[tid] = r0 | (r1 << 16);
    }

    // ---- stage BOTH windows up front (loads overlap), slot swizzle (ch+row)&7 ----
    {
        const bf16_t* srcP = phi_b + (size_t)(b * TC + t) * PLANE;
        const bf16_t* srcG = g_b   + (size_t)(b * TC + t) * PLANE;
        for (int idx = tid; idx < 1232; idx += 256) {
            const int row = idx >> 3;
            const int ch  = idx & 7;
            const int i   = row / 22;
            const int c   = row - i * 22;
            const size_t off = ((size_t)((X + i) * COLP) + Y0 + c) * NHEAD + ch * 8;
            const uint4 up = *(const uint4*)(srcP + off);
            const uint4 ug = *(const uint4*)(srcG + off);
            const int slot = row * 64 + (((ch + row) & 7) << 3);
            *(uint4*)&win1[slot] = up;
            *(uint4*)&win2[slot] = ug;
        }
    }
    __syncthreads();

    // ---- 49-key logits (win1) ----
    float v[4];
#pragma unroll
    for (int r = 0; r < 4; ++r) {
        const int k = sub + 16 * r;
        float d = -INFINITY;
        if (k < 49) {
            const int i = k / 7;
            const int j = k - i * 7;
            const int row = i * 22 + j + px;
            const bf16_t* base = &win1[row * 64];
            float s = 0.f;
#pragma unroll
            for (int ch = 0; ch < 8; ++ch) {
                const uint4 u = *(const uint4*)&base[((ch + row) & 7) << 3];
                s = dot2bf(u.x, qu[ch].x, s);
                s = dot2bf(u.y, qu[ch].y, s);
                s = dot2bf(u.z, qu[ch].z, s);
                s = dot2bf(u.w, qu[ch].w, s);
            }
            d = s * 8.0f;    // * sqrt(64)
        }
        v[r] = d;
    }
    float m = fmaxf(fmaxf(v[0], v[1]), fmaxf(v[2], v[3]));
#pragma unroll
    for (int d = 1; d < 16; d <<= 1) m = fmaxf(m, __shfl_xor(m, d));
    float lsum = 0.f;
#pragma unroll
    for (int r = 0; r < 4; ++r) {
        const int k = sub + 16 * r;
        if (k < 49) {
            const float e = __expf(v[r] - m);
            ls[px][k] = e;
            lsum += e;
        }
    }
#pragma unroll
    for (int d = 1; d < 16; d <<= 1) lsum += __shfl_xor(lsum, d);
    if (sub == 0) {
        *(float2*)&part_ml[((size_t)(b * TC + t) * HWPIX + gpix) * 2] = make_float2(m, lsum);
    }

    // pack weight pairs (same-wave ls traffic: no barrier)
#pragma unroll
    for (int mq = 0; mq < 2; ++mq) {
        const int mm = sub + 16 * mq;
        if (mm < 25) {
            const float a0 = ls[px][2 * mm];
            const float a1 = (2 * mm + 1 < 49) ? ls[px][2 * mm + 1] : 0.f;
            ls2[px][mm] = (unsigned)f2bf(a0) | ((unsigned)f2bf(a1) << 16);
        }
    }

    // ---- unnormalized y partial (win2): thread = (px, oct, par) ----
    {
        const int oct = sub >> 1;
        const int par = sub & 1;
        float acc[8];
#pragma unroll
        for (int e = 0; e < 8; ++e) acc[e] = 0.f;
#ifdef HAVE_DOT2
#pragma unroll
        for (int mm = 0; mm < 13; ++mm) {
            const int pm = 2 * mm + par;
            if (pm < 25) {
                const unsigned pr = prow[pm];
                const int row0 = (int)(pr & 0xFFFFu) + px;
                const int row1 = (int)(pr >> 16) + px;
                const unsigned a2 = ls2[px][pm];
                const uint4 u0 = *(const uint4*)&win2[row0 * 64 + (((oct + row0) & 7) << 3)];
                const uint4 u1 = *(const uint4*)&win2[row1 * 64 + (((oct + row1) & 7) << 3)];
                acc[0] = dot2bf(perm_lo(u1.x, u0.x), a2, acc[0]);
                acc[1] = dot2bf(perm_hi(u1.x, u0.x), a2, acc[1]);
                acc[2] = dot2bf(perm_lo(u1.y, u0.y), a2, acc[2]);
                acc[3] = dot2bf(perm_hi(u1.y, u0.y), a2, acc[3]);
                acc[4] = dot2bf(perm_lo(u1.z, u0.z), a2, acc[4]);
                acc[5] = dot2bf(perm_hi(u1.z, u0.z), a2, acc[5]);
                acc[6] = dot2bf(perm_lo(u1.w, u0.w), a2, acc[6]);
                acc[7] = dot2bf(perm_hi(u1.w, u0.w), a2, acc[7]);
            }
        }
#else
#pragma unroll
        for (int mm = 0; mm < 25; ++mm) {
            const int kk = 2 * mm + par;
            if (kk < 49) {
                const int i = kk / 7;
                const int j = kk - i * 7;
                const int row = i * 22 + j + px;
                const float a = ls[px][kk];
                const uint4 u = *(const uint4*)&win2[row * 64 + (((oct + row) & 7) << 3)];
                acc[0] = fmaf(a, bf_lo(u.x), acc[0]);
                acc[1] = fmaf(a, bf_hi(u.x), acc[1]);
                acc[2] = fmaf(a, bf_lo(u.y), acc[2]);
                acc[3] = fmaf(a, bf_hi(u.y), acc[3]);
                acc[4] = fmaf(a, bf_lo(u.z), acc[4]);
                acc[5] = fmaf(a, bf_hi(u.z), acc[5]);
                acc[6] = fmaf(a, bf_lo(u.w), acc[6]);
                acc[7] = fmaf(a, bf_hi(u.w), acc[7]);
            }
        }
#endif
#pragma unroll
        for (int e = 0; e < 8; ++e) acc[e] += __shfl_xor(acc[e], 1);
        if (par == 0) {
            uint4 o;
            o.x = (unsigned)f2bf(acc[0]) | ((unsigned)f2bf(acc[1]) << 16);
            o.y = (unsigned)f2bf(acc[2]) | ((unsigned)f2bf(acc[3]) << 16);
            o.z = (unsigned)f2bf(acc[4]) | ((unsigned)f2bf(acc[5]) << 16);
            o.w = (unsigned)f2bf(acc[6]) | ((unsigned)f2bf(acc[7]) << 16);
            *(uint4*)(part_y + ((size_t)(b * TC + t) * HWPIX + gpix) * NHEAD + (oct << 3)) = o;
        }
    }
}

// ---------------------------------------------------------------------------
// K3: combine 4 t-partials + out-proj + residual. Reads w_out directly
// (row-contiguous float4, L1-resident). Grid (3,48,8): z = b*4+cg.
// ---------------------------------------------------------------------------
__global__ __launch_bounds__(256) void combine_kernel(
    const float* __restrict__ x,
    const float* __restrict__ w_out,
    const float* __restrict__ part_ml,
    const bf16_t* __restrict__ part_y,
    float* __restrict__ out)
{
    __shared__ float y_s[16][68];

    const int tid = threadIdx.x;
    const int px  = tid >> 4;
    const int sub = tid & 15;
    const int Y0  = blockIdx.x * 16;
    const int X   = blockIdx.y;
    const int bz  = blockIdx.z;
    const int b   = bz >> 2;
    const int cg  = bz & 3;
    const int gpix = X * WW + Y0 + px;

    const float* mlb = part_ml + ((size_t)b * TC * HWPIX + gpix) * 2;
    float mt[TC], lt[TC];
#pragma unroll
    for (int t = 0; t < TC; ++t) {
        const float2 ml = *(const float2*)(mlb + (size_t)t * HWPIX * 2);
        mt[t] = ml.x; lt[t] = ml.y;
    }
    const float M = fmaxf(fmaxf(mt[0], mt[1]), fmaxf(mt[2], mt[3]));
    float st[TC], L = 0.f;
#pragma unroll
    for (int t = 0; t < TC; ++t) { st[t] = __expf(mt[t] - M); L += lt[t] * st[t]; }
    const float inv = 1.0f / L;
#pragma unroll
    for (int t = 0; t < TC; ++t) st[t] *= inv;

    float4 acc = make_float4(0.f, 0.f, 0.f, 0.f);
    const bf16_t* pyb = part_y + ((size_t)b * TC * HWPIX + gpix) * NHEAD + (sub << 2);
#pragma unroll
    for (int t = 0; t < TC; ++t) {
        const ushort4 u = *(const ushort4*)(pyb + (size_t)t * HWPIX * NHEAD);
        const float s = st[t];
        acc.x = fmaf(s, __uint_as_float(((unsigned)u.x) << 16), acc.x);
        acc.y = fmaf(s, __uint_as_float(((unsigned)u.y) << 16), acc.y);
        acc.z = fmaf(s, __uint_as_float(((unsigned)u.z) << 16), acc.z);
        acc.w = fmaf(s, __uint_as_float(((unsigned)u.w) << 16), acc.w);
    }
    *(float4*)&y_s[px][sub * 4] = acc;
    __syncthreads();

    {
        const int c0 = cg * 32 + sub * 2;
        const float4* wr0 = (const float4*)(w_out + (size_t)c0 * NHEAD);
        const float4* wr1 = (const float4*)(w_out + (size_t)(c0 + 1) * NHEAD);
        float o0 = 0.f, o1 = 0.f;
#pragma unroll 4
        for (int hq = 0; hq < 16; ++hq) {
            const float4 w0 = wr0[hq];
            const float4 w1 = wr1[hq];
            const float4 yv = *(const float4*)&y_s[px][hq * 4];
            o0 += w0.x*yv.x + w0.y*yv.y + w0.z*yv.z + w0.w*yv.w;
            o1 += w1.x*yv.x + w1.y*yv.y + w1.z*yv.z + w1.w*yv.w;
        }
        const float xi0 = x[((size_t)(b * CCH + c0    ) * TT) * HWPIX + gpix];
        const float xi1 = x[((size_t)(b * CCH + c0 + 1) * TT) * HWPIX + gpix];
        out[(size_t)(b * CCH + c0    ) * HWPIX + gpix] = xi0 + o0;
        out[(size_t)(b * CCH + c0 + 1) * HWPIX + gpix] = xi1 + o1;
    }
}

// ---------------------------------------------------------------------------
extern "C" void kernel_launch(void* const* d_in, const int* in_sizes, int n_in,
                              void* d_out, int out_size, void* d_ws, size_t ws_size,
                              hipStream_t stream)
{
    const float* x       = (const float*)d_in[0];
    const float* w_theta = (const float*)d_in[1];
    const float* w_phi   = (const float*)d_in[2];
    const float* w_g     = (const float*)d_in[3];
    const float* w_out   = (const float*)d_in[4];
    float* out = (float*)d_out;

    bf16_t* q_b    = (bf16_t*)d_ws;                              // 294912 us
    bf16_t* phi_b  = q_b + (size_t)BATCH * HWPIX * NHEAD;        // 1548288 us
    bf16_t* g_b    = phi_b + (size_t)BATCH * TC * PLANE;         // 1548288 us
    float*  part_ml = (float*)(g_b + (size_t)BATCH * TC * PLANE);// 36864 f
    bf16_t* part_y  = (bf16_t*)(part_ml + 36864);                // 1179648 us

    dim3 g1(HWPIX / 16, BATCH * TT);            // (144, 10)
    proj_kernel<<<g1, 256, 0, stream>>>(x, w_theta, w_phi, w_g, q_b, phi_b, g_b);

    attn_kernel<<<BATCH * TC * HH * (WW / 16), 256, 0, stream>>>(
        q_b, phi_b, g_b, part_ml, part_y);      // 1152 blocks

    dim3 g3(WW / 16, HH, BATCH * 4);            // (3, 48, 8)
    combine_kernel<<<g3, 256, 0, stream>>>(x, w_out, part_ml, part_y, out);
}